// Round 5
// baseline (95.535 us; speedup 1.0000x reference)
//
#include <hip/hip_runtime.h>
#include <hip/hip_bf16.h>

#define HH 256
#define WW 832
#define OHH 128
#define OWW 208
#define NCAND 240
#define MM (OHH*OWW)

typedef float v2f __attribute__((ext_vector_type(2)));

__device__ __forceinline__ int iclamp(int v, int lo, int hi) { return min(max(v, lo), hi); }
__device__ __forceinline__ int mbcnt64(unsigned long long m) {
    return __builtin_amdgcn_mbcnt_hi((unsigned)(m >> 32),
           __builtin_amdgcn_mbcnt_lo((unsigned)(m & 0xFFFFFFFFull), 0));
}

__global__ void __launch_bounds__(256) sa_fused(
    const float* __restrict__ pos1, const float* __restrict__ pos2,
    const float* __restrict__ w1, const float* __restrict__ b1,
    const float* __restrict__ w2, const float* __restrict__ b2,
    const float* __restrict__ w3, const float* __restrict__ b3,
    float* __restrict__ out)
{
    // weights as channel-pair float2 for v_pk_fma_f32
    __shared__ v2f sW1p[3][4];   // {w1[i][2op], w1[i][2op+1]}
    __shared__ v2f sW2p[8][4];
    __shared__ v2f sW3p[8][8];
    __shared__ v2f sB1p[4], sB2p[4], sB3p[8];
    __shared__ float4 selRel[128];   // 4 waves x 32 selected rel-coords

    const int t = threadIdx.x;
    if (t < 12)              { int i = t >> 2,  op = t & 3;
        sW1p[i][op] = (v2f){w1[i*8 + 2*op], w1[i*8 + 2*op + 1]}; }
    if (t >= 16 && t < 48)   { int u = t - 16, i = u >> 2, op = u & 3;
        sW2p[i][op] = (v2f){w2[i*8 + 2*op], w2[i*8 + 2*op + 1]}; }
    if (t >= 64 && t < 128)  { int u = t - 64, i = u >> 3, op = u & 7;
        sW3p[i][op] = (v2f){w3[i*16 + 2*op], w3[i*16 + 2*op + 1]}; }
    if (t >= 128 && t < 132) { int u = t - 128; sB1p[u] = (v2f){b1[2*u], b1[2*u + 1]}; }
    if (t >= 132 && t < 136) { int u = t - 132; sB2p[u] = (v2f){b2[2*u], b2[2*u + 1]}; }
    if (t >= 136 && t < 144) { int u = t - 136; sB3p[u] = (v2f){b3[2*u], b3[2*u + 1]}; }
    __syncthreads();

    const int lane = t & 63;
    const int wid  = t >> 6;
    const int m    = blockIdx.x * 4 + wid;      // 0..26623
    const int b    = blockIdx.y & 1;            // batch
    const int cl   = blockIdx.y >> 1;           // cloud (0 -> pos1, 1 -> pos2)
    const float* __restrict__ base = (cl ? pos2 : pos1) + (size_t)b * (HH * WW * 3);

    const unsigned um = (unsigned)m;
    const int oh = (int)(um / OWW);
    const int ow = (int)(um - (unsigned)oh * OWW);
    const int h0 = oh * 2, w0 = ow * 4;

    const float cx = base[(h0 * WW + w0) * 3 + 0];
    const float cy = base[(h0 * WW + w0) * 3 + 1];
    const float cz = base[(h0 * WW + w0) * 3 + 2];

    // ---- distances: candidate j = q*64 + lane, j in [0,240) ----
    // d2 >= 0 so the f32 bit pattern is order-preserving as unsigned.
    unsigned d2b[4];
    float dxv[4], dyv[4], dzv[4];
    #pragma unroll
    for (int q = 0; q < 4; ++q) {
        int j  = q * 64 + lane;
        int kh = (j * 205) >> 12;       // j / 20 for j < 256
        int kw = j - kh * 20;
        int ch = iclamp(h0 - 6 + kh, 0, HH - 1);
        int cw = iclamp(w0 - 10 + kw, 0, WW - 1);
        const float* p = base + (ch * WW + cw) * 3;
        float dx = __fsub_rn(p[0], cx);
        float dy = __fsub_rn(p[1], cy);
        float dz = __fsub_rn(p[2], cz);
        dxv[q] = dx; dyv[q] = dy; dzv[q] = dz;
        // match numpy f32 ordering exactly: (dx*dx + dy*dy) + dz*dz, no FMA
        float dd = __fadd_rn(__fadd_rn(__fmul_rn(dx, dx), __fmul_rn(dy, dy)), __fmul_rn(dz, dz));
        d2b[q] = (j < NCAND) ? __float_as_uint(dd) : 0xFFFFFFFFu;
    }

    // ---- radix-select the 32nd-smallest d2 (bit construction, ballot counting) ----
    // Selection SET equals stable top_k's: {d2 < T} plus lowest-index ties at T.
    unsigned T = 0;
    unsigned long long sm0 = 0, sm1 = 0, sm2 = 0, sm3 = 0;
    bool exact = false;
    for (int bpos = 30; bpos >= 0; --bpos) {   // d2 bits <= 0x7F800000, bit31 always 0
        unsigned Q = T | (1u << bpos);
        unsigned long long t0 = __ballot(d2b[0] < Q);
        unsigned long long t1 = __ballot(d2b[1] < Q);
        unsigned long long t2 = __ballot(d2b[2] < Q);
        unsigned long long t3 = __ballot(d2b[3] < Q);
        int c = __popcll(t0) + __popcll(t1) + __popcll(t2) + __popcll(t3);
        if (c == 32) { sm0 = t0; sm1 = t1; sm2 = t2; sm3 = t3; exact = true; break; }
        if (c < 32) T = Q;   // invariant: count(d2 < T) < 32
    }
    if (!exact) {
        // T is the 32nd smallest d2 value. Take all strictly-less, then the
        // lowest-index ties at T until 32 total (== stable top_k tie rule).
        unsigned long long l0 = __ballot(d2b[0] < T);
        unsigned long long l1 = __ballot(d2b[1] < T);
        unsigned long long l2 = __ballot(d2b[2] < T);
        unsigned long long l3 = __ballot(d2b[3] < T);
        unsigned long long e0 = __ballot(d2b[0] == T);
        unsigned long long e1 = __ballot(d2b[1] == T);
        unsigned long long e2 = __ballot(d2b[2] == T);
        unsigned long long e3 = __ballot(d2b[3] == T);
        int c_lt = __popcll(l0) + __popcll(l1) + __popcll(l2) + __popcll(l3);
        int r = 32 - c_lt;
        int p1 = __popcll(e0), p2 = p1 + __popcll(e1), p3 = p2 + __popcll(e2);
        bool s0 = (d2b[0] < T) || ((d2b[0] == T) && (mbcnt64(e0) < r));
        bool s1 = (d2b[1] < T) || ((d2b[1] == T) && (p1 + mbcnt64(e1) < r));
        bool s2 = (d2b[2] < T) || ((d2b[2] == T) && (p2 + mbcnt64(e2) < r));
        bool s3 = (d2b[3] < T) || ((d2b[3] == T) && (p3 + mbcnt64(e3) < r));
        sm0 = __ballot(s0); sm1 = __ballot(s1); sm2 = __ballot(s2); sm3 = __ballot(s3);
    }

    // ---- scatter the 32 winners' rel-coords to selRel[wid][rank] ----
    {
        int c1 = __popcll(sm0);
        int c2 = c1 + __popcll(sm1);
        int c3 = c2 + __popcll(sm2);
        int lb = wid * 32;
        if ((sm0 >> lane) & 1) selRel[lb +      mbcnt64(sm0)] = make_float4(dxv[0], dyv[0], dzv[0], 0.f);
        if ((sm1 >> lane) & 1) selRel[lb + c1 + mbcnt64(sm1)] = make_float4(dxv[1], dyv[1], dzv[1], 0.f);
        if ((sm2 >> lane) & 1) selRel[lb + c2 + mbcnt64(sm2)] = make_float4(dxv[2], dyv[2], dzv[2], 0.f);
        if ((sm3 >> lane) & 1) selRel[lb + c3 + mbcnt64(sm3)] = make_float4(dxv[3], dyv[3], dzv[3], 0.f);
    }
    // same-wave LDS visibility: drain DS pipe, fence the scheduler
    asm volatile("s_waitcnt lgkmcnt(0)" ::: "memory");
    __builtin_amdgcn_sched_barrier(0);

    // ---- MLP: lane l and l+32 process neighbor (l&31); halves split layer-3 channels ----
    {
        float4 rel = selRel[wid * 32 + (lane & 31)];
        v2f rx2 = (v2f){rel.x, rel.x};
        v2f ry2 = (v2f){rel.y, rel.y};
        v2f rz2 = (v2f){rel.z, rel.z};

        v2f a1[4];
        #pragma unroll
        for (int op = 0; op < 4; ++op) {
            v2f a = sB1p[op];
            a = __builtin_elementwise_fma(rx2, sW1p[0][op], a);
            a = __builtin_elementwise_fma(ry2, sW1p[1][op], a);
            a = __builtin_elementwise_fma(rz2, sW1p[2][op], a);
            a1[op] = __builtin_elementwise_max(a, (v2f)(0.f));
        }
        v2f a2[4];
        #pragma unroll
        for (int op = 0; op < 4; ++op) a2[op] = sB2p[op];
        #pragma unroll
        for (int i = 0; i < 8; ++i) {
            float h = a1[i >> 1][i & 1];
            v2f hb = (v2f){h, h};
            #pragma unroll
            for (int op = 0; op < 4; ++op)
                a2[op] = __builtin_elementwise_fma(hb, sW2p[i][op], a2[op]);
        }
        #pragma unroll
        for (int op = 0; op < 4; ++op) a2[op] = __builtin_elementwise_max(a2[op], (v2f)(0.f));

        const int obp = (lane >> 5) << 2;   // pair offset: lanes 0-31 ch 0-7, lanes 32-63 ch 8-15
        v2f a3[4];
        #pragma unroll
        for (int op = 0; op < 4; ++op) a3[op] = sB3p[obp + op];
        #pragma unroll
        for (int i = 0; i < 8; ++i) {
            float h = a2[i >> 1][i & 1];
            v2f hb = (v2f){h, h};
            #pragma unroll
            for (int op = 0; op < 4; ++op)
                a3[op] = __builtin_elementwise_fma(hb, sW3p[i][obp + op], a3[op]);
        }
        float h3[8];
        #pragma unroll
        for (int o = 0; o < 8; ++o) h3[o] = a3[o >> 1][o & 1];  // relu deferred past max-pool

        // max over the 32 neighbor-lanes within each half (xor<=16 keeps halves separate)
        #pragma unroll
        for (int o = 0; o < 8; ++o) {
            h3[o] = fmaxf(h3[o], __shfl_xor(h3[o], 16));
            h3[o] = fmaxf(h3[o], __shfl_xor(h3[o], 8));
            h3[o] = fmaxf(h3[o], __shfl_xor(h3[o], 4));
            h3[o] = fmaxf(h3[o], __shfl_xor(h3[o], 2));
            h3[o] = fmaxf(h3[o], __shfl_xor(h3[o], 1));
        }
        if ((lane & 31) == 0) {
            const int ob = (lane >> 5) << 3;
            float4* dst = (float4*)(out + ((size_t)(b * MM + m) * 32) + (size_t)cl * 16 + ob);
            dst[0] = make_float4(fmaxf(h3[0], 0.f), fmaxf(h3[1], 0.f), fmaxf(h3[2], 0.f), fmaxf(h3[3], 0.f));
            dst[1] = make_float4(fmaxf(h3[4], 0.f), fmaxf(h3[5], 0.f), fmaxf(h3[6], 0.f), fmaxf(h3[7], 0.f));
        }
    }
}

extern "C" void kernel_launch(void* const* d_in, const int* in_sizes, int n_in,
                              void* d_out, int out_size, void* d_ws, size_t ws_size,
                              hipStream_t stream) {
    const float* pos1 = (const float*)d_in[0];
    const float* pos2 = (const float*)d_in[1];
    const float* w1   = (const float*)d_in[2];
    const float* b1   = (const float*)d_in[3];
    const float* w2   = (const float*)d_in[4];
    const float* b2   = (const float*)d_in[5];
    const float* w3   = (const float*)d_in[6];
    const float* b3   = (const float*)d_in[7];
    float* out = (float*)d_out;

    dim3 grid(MM / 4, 4);   // 6656 blocks x {batch, cloud}
    sa_fused<<<grid, 256, 0, stream>>>(pos1, pos2, w1, b1, w2, b2, w3, b3, out);
}